// Round 2
// baseline (1048.433 us; speedup 1.0000x reference)
//
#include <hip/hip_runtime.h>

typedef unsigned short u16;
typedef unsigned int u32;
typedef __attribute__((ext_vector_type(8))) short s16x8;
typedef __attribute__((ext_vector_type(8))) __bf16 bf16x8;
typedef __attribute__((ext_vector_type(8))) float f32x8;
typedef __attribute__((ext_vector_type(4))) float f32x4;

__device__ inline u16 f2bf(float f) {
  union { float f; u32 i; } v; v.f = f;
  return (u16)((v.i + 0x8000u) >> 16);   // round-half-up, cheap (2 VALU)
}
__device__ inline s16x8 ld8(const u16* p) { return *reinterpret_cast<const s16x8*>(p); }
__device__ inline s16x8 cvt8(f32x8 a) {
  s16x8 r;
#pragma unroll
  for (int i = 0; i < 8; ++i) r[i] = (short)f2bf(a[i]);
  return r;
}
__device__ inline f32x4 mfma16(s16x8 a, s16x8 b, f32x4 c) {
  return __builtin_amdgcn_mfma_f32_16x16x32_bf16(
      __builtin_bit_cast(bf16x8, a), __builtin_bit_cast(bf16x8, b), c, 0, 0, 0);
}

// ---- pooledT[16][512] bf16: rows 0-7 = mean(style[n,s,0:3,0:3]); rows 8-15 = 0 ----
__global__ void k_pooled(const float* __restrict__ style, u16* __restrict__ pooledT) {
  int t = blockIdx.x * 256 + threadIdx.x;    // grid 32 -> t in [0,8192)
  if (t < 4096) {
    const float* b = style + t * 25;
    float s = 0.f;
#pragma unroll
    for (int i = 0; i < 3; ++i)
#pragma unroll
      for (int j = 0; j < 3; ++j) s += b[i * 5 + j];
    pooledT[t] = f2bf(s * (1.f / 9.f));
  } else {
    pooledT[t] = 0;
  }
}

// ---- Bt (80 x 4608) bf16 im2col of style; rows >=72 zero ----
__global__ void k_im2col(const float* __restrict__ style, u16* __restrict__ Bt) {
  int idx = blockIdx.x * 256 + threadIdx.x;  // grid 1440*256 = 368640 = 80*4608
  int row = idx / 4608;
  int k = idx - row * 4608;
  u16 v = 0;
  if (row < 72) {
    int n = row / 9; int r9 = row - n * 9;
    int rr = r9 / 3; int cc = r9 - rr * 3;
    int s = k / 9;  int rc = k - s * 9;
    int i = rc / 3; int j = rc - i * 3;
    v = f2bf(style[(n * 512 + s) * 25 + (rr + i) * 5 + (cc + j)]);
  }
  Bt[idx] = v;
}

// ---- pw GEMMs via MFMA: C[M,16] = W[M,512] x pooledT^T; blocks<512: Wpwk, else Wpwb ----
__global__ __launch_bounds__(256) void k_pw(const u16* __restrict__ pooledT,
    const float* __restrict__ Wpwk, const float* __restrict__ bpwk,
    const float* __restrict__ Wpwb, const float* __restrict__ bpwb,
    u16* __restrict__ pwk_out, float* __restrict__ pwb_out) {
  int lane = threadIdx.x & 63, wave = threadIdx.x >> 6;
  int li = lane & 15, q = lane >> 4;
  int b = blockIdx.x;                        // grid 520
  bool is_k = (b < 512);
  int m_base = (is_k ? b : (b - 512)) * 64 + wave * 16;
  const float* A = is_k ? Wpwk : Wpwb;
  const float* bias = is_k ? bpwk : bpwb;
  const float* Ap = A + (size_t)(m_base + li) * 512 + q * 8;
  const u16* Bp = pooledT + li * 512 + q * 8;
  f32x4 acc = {};
  for (int k0 = 0; k0 < 512; k0 += 32) {
    f32x8 af = *reinterpret_cast<const f32x8*>(Ap + k0);
    s16x8 bfrag = ld8(Bp + k0);
    acc = mfma16(cvt8(af), bfrag, acc);
  }
  if (li < 8) {                              // samples 0-7 are real
#pragma unroll
    for (int r = 0; r < 4; ++r) {
      int o = m_base + q * 4 + r;
      float v = acc[r] + bias[o];
      if (is_k) pwk_out[li * 32768 + o] = f2bf(v);
      else      pwb_out[li * 512 + o] = v;
    }
  }
}

// ---- dk GEMM: (32768 x 4608 f32) x (4608 x 80 bf16) -> dkw2[n][rc][o'] bf16 ----
// 4-deep software-pipelined A prefetch ring: keeps ~8 KB/wave of HBM loads in
// flight (64 KB/CU at 8 waves/CU) to cover ~900-cycle HBM latency. Ring is
// statically indexed (unrolled u-loop) so it stays in VGPRs, not scratch.
__global__ __launch_bounds__(256) void k_dkgemm(const float* __restrict__ A,
    const u16* __restrict__ Bt, const float* __restrict__ bdk,
    u16* __restrict__ dkw2) {
  int lane = threadIdx.x & 63;
  int wave = threadIdx.x >> 6;
  int li = lane & 15, q = lane >> 4;
  int m_base = blockIdx.x * 64 + wave * 16;  // grid 512: 32768 rows
  const float* Ap = A + (size_t)(m_base + li) * 4608 + q * 8;
  const u16* Bp = Bt + (size_t)li * 4608 + q * 8;
  f32x4 acc[5] = {};
  f32x8 buf0 = *reinterpret_cast<const f32x8*>(Ap);
  f32x8 buf1 = *reinterpret_cast<const f32x8*>(Ap + 32);
  f32x8 buf2 = *reinterpret_cast<const f32x8*>(Ap + 64);
  f32x8 buf3 = *reinterpret_cast<const f32x8*>(Ap + 96);
#define DK_BODY(BUF, KOFF, REFILL)                                   \
  {                                                                  \
    s16x8 av = cvt8(BUF);                                            \
    if (REFILL) BUF = *reinterpret_cast<const f32x8*>(Ap + (KOFF) + 128); \
    s16x8 b0 = ld8(Bp + (KOFF));                                     \
    s16x8 b1 = ld8(Bp + 16 * 4608 + (KOFF));                         \
    s16x8 b2 = ld8(Bp + 32 * 4608 + (KOFF));                         \
    s16x8 b3 = ld8(Bp + 48 * 4608 + (KOFF));                         \
    s16x8 b4 = ld8(Bp + 64 * 4608 + (KOFF));                         \
    acc[0] = mfma16(av, b0, acc[0]);                                 \
    acc[1] = mfma16(av, b1, acc[1]);                                 \
    acc[2] = mfma16(av, b2, acc[2]);                                 \
    acc[3] = mfma16(av, b3, acc[3]);                                 \
    acc[4] = mfma16(av, b4, acc[4]);                                 \
  }
#pragma unroll 1
  for (int k0 = 0; k0 < 4608 - 128; k0 += 128) {
    DK_BODY(buf0, k0 + 0, true)
    DK_BODY(buf1, k0 + 32, true)
    DK_BODY(buf2, k0 + 64, true)
    DK_BODY(buf3, k0 + 96, true)
  }
  {
    const int k0 = 4608 - 128;
    DK_BODY(buf0, k0 + 0, false)
    DK_BODY(buf1, k0 + 32, false)
    DK_BODY(buf2, k0 + 64, false)
    DK_BODY(buf3, k0 + 96, false)
  }
#undef DK_BODY
  float bias_r[4];
#pragma unroll
  for (int r = 0; r < 4; ++r) bias_r[r] = bdk[m_base + q * 4 + r];
#pragma unroll
  for (int t = 0; t < 5; ++t) {
    int col = t * 16 + li;
    if (col >= 72) continue;
    int nn = col / 9; int rc = col - nn * 9;
    u16* outb = dkw2 + (size_t)(nn * 9 + rc) * 32768;
#pragma unroll
    for (int r = 0; r < 4; ++r) {
      int row = m_base + q * 4 + r;
      outb[row] = f2bf(acc[t][r] + bias_r[r]);
    }
  }
}

// ---- fused depthwise 3x3 (reflect pad) + grouped 1x1 + bias; f32 out ----
__global__ __launch_bounds__(256) void k_fused(const float* __restrict__ pred,
    const u16* __restrict__ dkw2, const u16* __restrict__ pwk,
    const float* __restrict__ pwb, float* __restrict__ out) {
  __shared__ u16 lds_in[3 * 64 * 72];   // [r3][x][c], stride 72 (2-way bank alias only)
  __shared__ u16 lds2[64 * 72];         // depth transposed [p][c]
  int bid = blockIdx.x;                 // grid 4096 = 8n * 8g * 64yy
  int yy = bid & 63; int g = (bid >> 6) & 7; int n = bid >> 9;
  int tid = threadIdx.x;
  for (int idx = tid; idx < 3 * 64 * 64; idx += 256) {
    int x = idx & 63;
    int t2 = idx >> 6;
    int c = t2 & 63;
    int r3 = t2 >> 6;
    int sy = yy + r3 - 1; sy = sy < 0 ? 1 : (sy > 63 ? 62 : sy);   // reflect pad
    lds_in[(r3 * 64 + x) * 72 + c] =
        f2bf(pred[((size_t)((n * 512 + g * 64 + c) * 64 + sy)) * 64 + x]);
  }
  __syncthreads();
  int lane = tid & 63; int wave = tid >> 6;
  int li = lane & 15, q = lane >> 4;
  f32x4 acc[4] = {};
#pragma unroll
  for (int rc = 0; rc < 9; ++rc) {
    int di = rc / 3, dj = rc - (rc / 3) * 3;
    const u16* Ap = dkw2 + (size_t)(n * 9 + rc) * 32768 +
                    (g * 64 + wave * 16 + li) * 64 + q * 8;
#pragma unroll
    for (int kk = 0; kk < 2; ++kk) {
      s16x8 a = ld8(Ap + kk * 32);
#pragma unroll
      for (int tn = 0; tn < 4; ++tn) {
        int p = tn * 16 + li;
        int sx = p + dj - 1; sx = sx < 0 ? 1 : (sx > 63 ? 62 : sx); // reflect pad
        s16x8 b = *reinterpret_cast<const s16x8*>(
            &lds_in[(di * 64 + sx) * 72 + kk * 32 + q * 8]);
        acc[tn] = mfma16(a, b, acc[tn]);
      }
    }
  }
#pragma unroll
  for (int tn = 0; tn < 4; ++tn) {
    int p = tn * 16 + li;
#pragma unroll
    for (int r = 0; r < 4; ++r) {
      int cch = wave * 16 + q * 4 + r;
      lds2[p * 72 + cch] = f2bf(acc[tn][r]);
    }
  }
  __syncthreads();
  f32x4 acc2[4] = {};
  const u16* A2 = pwk + (size_t)n * 32768 + (g * 64 + wave * 16 + li) * 64 + q * 8;
#pragma unroll
  for (int kk = 0; kk < 2; ++kk) {
    s16x8 a = ld8(A2 + kk * 32);
#pragma unroll
    for (int tn = 0; tn < 4; ++tn) {
      s16x8 b = *reinterpret_cast<const s16x8*>(
          &lds2[(tn * 16 + li) * 72 + kk * 32 + q * 8]);
      acc2[tn] = mfma16(a, b, acc2[tn]);
    }
  }
  float bias_r[4];
#pragma unroll
  for (int r = 0; r < 4; ++r)
    bias_r[r] = pwb[n * 512 + g * 64 + wave * 16 + q * 4 + r];
#pragma unroll
  for (int tn = 0; tn < 4; ++tn) {
    int x = tn * 16 + li;
#pragma unroll
    for (int r = 0; r < 4; ++r) {
      int og = g * 64 + wave * 16 + q * 4 + r;
      out[((size_t)(n * 512 + og) * 64 + yy) * 64 + x] = acc2[tn][r] + bias_r[r];
    }
  }
}

extern "C" void kernel_launch(void* const* d_in, const int* in_sizes, int n_in,
                              void* d_out, int out_size, void* d_ws, size_t ws_size,
                              hipStream_t stream) {
  const float* style = (const float*)d_in[0];   // (8,512,5,5)
  const float* pred  = (const float*)d_in[1];   // (8,512,64,64)
  const float* Wdk   = (const float*)d_in[2];   // (32768,512,3,3) = (32768,4608)
  const float* bdk   = (const float*)d_in[3];   // (32768)
  const float* Wpwk  = (const float*)d_in[4];   // (32768,512)
  const float* bpwk  = (const float*)d_in[5];   // (32768)
  const float* Wpwb  = (const float*)d_in[6];   // (512,512)
  const float* bpwb  = (const float*)d_in[7];   // (512)
  float* outp = (float*)d_out;

  char* ws = (char*)d_ws;
  u16*   pooledT = (u16*)(ws);              // 16*512*2   = 16384 B
  float* pwb_o   = (float*)(ws + 16384);    // 8*512*4    = 16384 B
  u16*   Bt      = (u16*)(ws + 32768);      // 80*4608*2  = 737280 B
  u16*   pwk_o   = (u16*)(ws + 770048);     // 8*32768*2  = 524288 B
  u16*   dkw2    = (u16*)(ws + 1294336);    // 72*32768*2 = 4718592 B (~5.7 MB total)

  hipLaunchKernelGGL(k_pooled, dim3(32),   dim3(256), 0, stream, style, pooledT);
  hipLaunchKernelGGL(k_im2col, dim3(1440), dim3(256), 0, stream, style, Bt);
  hipLaunchKernelGGL(k_pw,     dim3(520),  dim3(256), 0, stream,
                     pooledT, Wpwk, bpwk, Wpwb, bpwb, pwk_o, pwb_o);
  hipLaunchKernelGGL(k_dkgemm, dim3(512),  dim3(256), 0, stream, Wdk, Bt, bdk, dkw2);
  hipLaunchKernelGGL(k_fused,  dim3(4096), dim3(256), 0, stream,
                     pred, dkw2, pwk_o, pwb_o, outp);
}